// Round 5
// baseline (327.550 us; speedup 1.0000x reference)
//
#include <hip/hip_runtime.h>
#include <cstdint>
#include <cstddef>

// Problem constants: B=8, S=2048, H=512, M=4096 -> R = B*S = 16384 rows.
#define H_DIM   512
#define M_DIM   4096

typedef unsigned short u16;
typedef short bf16x8 __attribute__((ext_vector_type(8)));   // 8 bf16 in 4 VGPRs
typedef float f32x4  __attribute__((ext_vector_type(4)));

typedef const __attribute__((address_space(1))) void* gp_t;
typedef __attribute__((address_space(3))) void* lp_t;

// fp32 -> bf16 round-to-nearest-even
__device__ __forceinline__ u16 f2b(float f) {
  union { float f; uint32_t u; } v; v.f = f;
  uint32_t u = v.u + (0x7FFFu + ((v.u >> 16) & 1u));
  return (u16)(u >> 16);
}

// ---------------- elementwise fp32 -> bf16 (n4 = n/4 float4 groups) ----------
__global__ void k_f2bf(const float* __restrict__ in, u16* __restrict__ out, int n4) {
  int i = blockIdx.x * blockDim.x + threadIdx.x;
  if (i < n4) {
    float4 v = ((const float4*)in)[i];
    ushort4 o;
    o.x = f2b(v.x); o.y = f2b(v.y); o.z = f2b(v.z); o.w = f2b(v.w);
    ((ushort4*)out)[i] = o;
  }
}

// ---- compaction: scan usage[4096] -> idx map + meta -------------------------
// meta[0]=count, meta[1]=K_eff=round256(count), meta[2]=K_eff/32, meta[3]=K_eff/256
__global__ void k_compact(const int* __restrict__ usage, int* __restrict__ idx,
                          int* __restrict__ meta) {
  __shared__ int cnt[256];
  int t = threadIdx.x;
  int base = t * 16;
  int c = 0;
  #pragma unroll
  for (int i = 0; i < 16; ++i) c += (usage[base + i] > 0) ? 1 : 0;
  cnt[t] = c;
  __syncthreads();
  for (int d = 1; d < 256; d <<= 1) {           // inclusive Hillis-Steele scan
    int v = (t >= d) ? cnt[t - d] : 0;
    __syncthreads();
    cnt[t] += v;
    __syncthreads();
  }
  int pos = cnt[t] - c;                          // exclusive prefix
  for (int i = 0; i < 16; ++i)
    if (usage[base + i] > 0) idx[pos++] = base + i;
  if (t == 0) {
    int total = cnt[255];
    int keff = ((total + 255) >> 8) << 8;        // 256-granular padding
    meta[0] = total; meta[1] = keff; meta[2] = keff >> 5; meta[3] = keff >> 8;
  }
}

// ---- gather + L2-normalize keys into compacted bank (zeros padding) ---------
__global__ void k_gather_norm(const float* __restrict__ in, const int* __restrict__ idx,
                              const int* __restrict__ meta, u16* __restrict__ out) {
  int j    = blockIdx.x * 4 + (threadIdx.x >> 6);
  int lane = threadIdx.x & 63;
  int count = meta[0];
  ushort4* op = (ushort4*)(out + (size_t)j * H_DIM);
  if (j >= count) {                 // wave-uniform
    ushort4 z = {0, 0, 0, 0};
    op[lane] = z; op[lane + 64] = z;
    return;
  }
  int src = idx[j];
  const float4* rp = (const float4*)(in + (size_t)src * H_DIM);
  float4 a = rp[lane];
  float4 b = rp[lane + 64];
  float ss = a.x*a.x + a.y*a.y + a.z*a.z + a.w*a.w
           + b.x*b.x + b.y*b.y + b.z*b.z + b.w*b.w;
  #pragma unroll
  for (int d = 1; d < 64; d <<= 1) ss += __shfl_xor(ss, d, 64);
  float s = rsqrtf(ss + 1e-6f);
  ushort4 oa, ob;
  oa.x = f2b(a.x*s); oa.y = f2b(a.y*s); oa.z = f2b(a.z*s); oa.w = f2b(a.w*s);
  ob.x = f2b(b.x*s); ob.y = f2b(b.y*s); ob.z = f2b(b.z*s); ob.w = f2b(b.w*s);
  op[lane]      = oa;
  op[lane + 64] = ob;
}

// ---- gather + convert: mvals fp32 rows -> compacted bf16 rows (zero pad) ----
__global__ void k_gather(const float* __restrict__ in, const int* __restrict__ idx,
                         const int* __restrict__ meta, u16* __restrict__ out) {
  int j    = blockIdx.x * 4 + (threadIdx.x >> 6);
  int lane = threadIdx.x & 63;
  int count = meta[0];
  ushort4* op = (ushort4*)(out + (size_t)j * H_DIM);
  if (j >= count) {                 // wave-uniform
    ushort4 z = {0, 0, 0, 0};
    op[lane] = z; op[lane + 64] = z;
    return;
  }
  int src = idx[j];
  const float4* rp = (const float4*)(in + (size_t)src * H_DIM);
  float4 a = rp[lane];
  float4 b = rp[lane + 64];
  ushort4 oa, ob;
  oa.x = f2b(a.x); oa.y = f2b(a.y); oa.z = f2b(a.z); oa.w = f2b(a.w);
  ob.x = f2b(b.x); ob.y = f2b(b.y); ob.z = f2b(b.z); ob.w = f2b(b.w);
  op[lane]      = oa;
  op[lane + 64] = ob;
}

// ---- rsqQ[r] = rsqrt(sum of 4 qss partials + eps) ---------------------------
__global__ void k_rsq(const float* __restrict__ qss, float* __restrict__ rsq) {
  int r = blockIdx.x * blockDim.x + threadIdx.x;
  float s = qss[r*4] + qss[r*4+1] + qss[r*4+2] + qss[r*4+3];
  rsq[r] = rsqrtf(s + 1e-6f);
}

// ---- reduce partial row sums -> reciprocal (npart = meta[3] 256-chunks) -----
__global__ void k_reduce_l(const float* __restrict__ lpart, float* __restrict__ linv,
                           const int* __restrict__ meta) {
  int r = blockIdx.x * blockDim.x + threadIdx.x;
  int n = meta[3];
  float s = 0.0f;
  for (int i = 0; i < n; ++i) s += lpart[(size_t)r * 32 + i];
  linv[r] = 1.0f / s;
}

// =============================================================================
// BT-layout GEMM: C[r,n] = sum_k A[r,k] * B[n,k]
// Template: NCB = col-128-blocks per tile (1 or 2), BK = k-chunk (32 or 64).
// 128 x (128*NCB) tile, 256 threads = 4 waves; wave w covers rows (w>>1)*64,
// cols (w&1)*(TN/2); 16x16x32 MFMA, acc[4][NJ] (NJ = TN/32).
// Conflict-free LDS: 16-row slab stored [kc(BK/32)][chunk(4)][row(16)][8];
// staged via global_load_lds, lane -> (row=lane&15, chunk=lane>>4).
// Fewer/bigger k-iters (BK=64) halve barrier-drain events — the measured
// ~50% stall at MfmaUtil 14%.
//
// EPI_QPROJ: out qb bf16 = C + bias; per-row partial sumsq -> aux[row*4+cb]
// EPI_MW   : out MWt bf16 = C  (cb-loop over meta[1]/128, step 16)
// EPI_P    : XCD-swizzled rb; NCB=2; P = (n<count) ? exp(10*C*rowscale[r]) : 0;
//            per-row partial sums -> aux[row*32+cb]  (cb = 256-chunk id)
// EPI_OUT  : XCD-swizzled rb; kel=meta[1]; outf = C*rowscale[r] + bias[n] (fp32)
// =============================================================================
#define EPI_QPROJ 0
#define EPI_MW    1
#define EPI_P     2
#define EPI_OUT   3

template<int EPI, int NCB, int BK>
__global__ __launch_bounds__(256)
void k_gemm_bt(const u16* __restrict__ A, const u16* __restrict__ B,
               int N, int K,
               const int* __restrict__ meta,
               float* __restrict__ outf, u16* __restrict__ outh,
               const float* __restrict__ bias,
               float* __restrict__ aux,
               const float* __restrict__ rowscale) {
  constexpr int TN = 128 * NCB;     // tile width
  constexpr int KS = BK / 32;       // 32-wide k-steps per staged chunk
  constexpr int NJ = TN / 32;       // 16-col tiles per wave
  __shared__ u16 Ah[128 * BK];
  __shared__ u16 Bh[TN * BK];
  __shared__ float lsh[128];

  const int tid  = threadIdx.x;
  const int wave = tid >> 6, lane = tid & 63;
  const int wr = (wave >> 1) * 64;
  const int wc = (wave & 1) * (TN / 2);

  int rb, cb0, cb_end, cb_step, kel;
  if (EPI == EPI_QPROJ) {
    rb = blockIdx.y; cb0 = blockIdx.x; cb_end = cb0 + 1; cb_step = 1; kel = K;
  } else if (EPI == EPI_MW) {
    rb = blockIdx.y; cb0 = blockIdx.x; cb_end = meta[1] >> 7; cb_step = 16; kel = K;
  } else if (EPI == EPI_P) {
    // grid (8,128): all 8 col-chunks of a row-block on one XCD
    int id = blockIdx.x + (blockIdx.y << 3);
    int xcd = id & 7, s = id >> 3;
    rb = xcd * 16 + (s >> 3); cb0 = s & 7;
    cb_end = meta[1] >> 8; cb_step = 8; kel = K;
  } else { // EPI_OUT
    // grid (4,128): the 4 col-blocks of a row-block on one XCD
    int id = blockIdx.x + (blockIdx.y << 2);
    int xcd = id & 7, s = id >> 3;
    rb = xcd * 16 + (s >> 2); cb0 = s & 3;
    cb_end = cb0 + 1; cb_step = 1; kel = meta[1];
  }
  const int row0 = rb << 7;
  const int kiters = kel / BK;

  // staging lane map: row = lane&15 within a 16-row slab, 32-col chunk = lane>>4
  const int srow   = lane & 15;
  const int schunk = lane >> 4;
  size_t aBase[2];
  #pragma unroll
  for (int s2 = 0; s2 < 2; ++s2)
    aBase[s2] = (size_t)(row0 + (wave + s2 * 4) * 16 + srow) * (size_t)K + schunk * 8;

  const int fr = lane & 15;                       // fragment row/col within 16
  const int fbase = (lane >> 4) * 128 + fr * 8;   // LDS fragment offset

  for (int cb = cb0; cb < cb_end; cb += cb_step) {
    const int col0 = cb * TN;
    __syncthreads();                              // guard lsh/LDS reuse across cb
    if ((EPI == EPI_QPROJ || EPI == EPI_P) && tid < 128) lsh[tid] = 0.0f;

    size_t bBase[TN / 64];
    #pragma unroll
    for (int s2 = 0; s2 < TN / 64; ++s2)
      bBase[s2] = (size_t)(col0 + (wave + s2 * 4) * 16 + srow) * (size_t)K + schunk * 8;

    f32x4 acc[4][NJ];
    const f32x4 z = {0.0f, 0.0f, 0.0f, 0.0f};
    #pragma unroll
    for (int i = 0; i < 4; ++i)
      #pragma unroll
      for (int j = 0; j < NJ; ++j) acc[i][j] = z;

    for (int it = 0; it < kiters; ++it) {
      const int k0 = it * BK;
      __syncthreads();   // prior iteration's LDS reads drained
      #pragma unroll
      for (int s2 = 0; s2 < 2; ++s2)
        #pragma unroll
        for (int kc = 0; kc < KS; ++kc)
          __builtin_amdgcn_global_load_lds((gp_t)(A + aBase[s2] + k0 + kc * 32),
              (lp_t)&Ah[(wave + s2 * 4) * (16 * BK) + kc * 512], 16, 0, 0);
      #pragma unroll
      for (int s2 = 0; s2 < TN / 64; ++s2)
        #pragma unroll
        for (int kc = 0; kc < KS; ++kc)
          __builtin_amdgcn_global_load_lds((gp_t)(B + bBase[s2] + k0 + kc * 32),
              (lp_t)&Bh[(wave + s2 * 4) * (16 * BK) + kc * 512], 16, 0, 0);
      __syncthreads();   // staging drained (vmcnt(0) before barrier)

      #pragma unroll
      for (int ks = 0; ks < KS; ++ks) {
        const int ko = ks * 512;
        bf16x8 af[4], bfv[NJ];
        #pragma unroll
        for (int i = 0; i < 4; ++i)
          af[i] = *(const bf16x8*)&Ah[((wr >> 4) + i) * (16 * BK) + ko + fbase];
        #pragma unroll
        for (int j = 0; j < NJ; ++j)
          bfv[j] = *(const bf16x8*)&Bh[((wc >> 4) + j) * (16 * BK) + ko + fbase];
        #pragma unroll
        for (int i = 0; i < 4; ++i)
          #pragma unroll
          for (int j = 0; j < NJ; ++j)
            acc[i][j] = __builtin_amdgcn_mfma_f32_16x16x32_bf16(af[i], bfv[j], acc[i][j], 0, 0, 0);
      }
    }

    // Epilogue. C/D layout per 16x16 tile: col = lane&15, row = (lane>>4)*4 + reg.
    if (EPI == EPI_QPROJ) {
      float bv[NJ];
      #pragma unroll
      for (int j = 0; j < NJ; ++j) bv[j] = bias[col0 + wc + j * 16 + fr];
      #pragma unroll
      for (int i = 0; i < 4; ++i) {
        #pragma unroll
        for (int r = 0; r < 4; ++r) {
          int lrow = wr + i * 16 + (lane >> 4) * 4 + r;
          size_t grow = (size_t)(row0 + lrow);
          float s = 0.0f;
          #pragma unroll
          for (int j = 0; j < NJ; ++j) {
            int gcol = col0 + wc + j * 16 + fr;
            float v = acc[i][j][r] + bv[j];
            outh[grow * (size_t)N + gcol] = f2b(v);
            s += v * v;
          }
          #pragma unroll
          for (int d = 1; d < 16; d <<= 1) s += __shfl_xor(s, d, 64);
          if (fr == 0) atomicAdd(&lsh[lrow], s);
        }
      }
      __syncthreads();
      if (tid < 128) aux[(size_t)(row0 + tid) * 4 + cb] = lsh[tid];
    } else if (EPI == EPI_MW) {
      #pragma unroll
      for (int i = 0; i < 4; ++i) {
        #pragma unroll
        for (int r = 0; r < 4; ++r) {
          int grow = row0 + wr + i * 16 + (lane >> 4) * 4 + r;
          #pragma unroll
          for (int j = 0; j < NJ; ++j) {
            int gcol = col0 + wc + j * 16 + fr;
            outh[(size_t)grow * (size_t)N + gcol] = f2b(acc[i][j][r]);
          }
        }
      }
    } else if (EPI == EPI_P) {
      const int count = meta[0];
      #pragma unroll
      for (int i = 0; i < 4; ++i) {
        #pragma unroll
        for (int r = 0; r < 4; ++r) {
          int lrow = wr + i * 16 + (lane >> 4) * 4 + r;
          size_t grow = (size_t)(row0 + lrow);
          float rq10 = rowscale[grow] * 10.0f;
          float s = 0.0f;
          #pragma unroll
          for (int j = 0; j < NJ; ++j) {
            int gcol = col0 + wc + j * 16 + fr;
            float p = (gcol < count) ? __expf(acc[i][j][r] * rq10) : 0.0f;
            outh[grow * (size_t)N + gcol] = f2b(p);
            s += p;
          }
          #pragma unroll
          for (int d = 1; d < 16; d <<= 1) s += __shfl_xor(s, d, 64);
          if (fr == 0) atomicAdd(&lsh[lrow], s);
        }
      }
      __syncthreads();
      if (tid < 128) aux[(size_t)(row0 + tid) * 32 + cb] = lsh[tid];
    } else {  // EPI_OUT
      float bv[NJ];
      #pragma unroll
      for (int j = 0; j < NJ; ++j) bv[j] = bias[col0 + wc + j * 16 + fr];
      #pragma unroll
      for (int i = 0; i < 4; ++i) {
        #pragma unroll
        for (int r = 0; r < 4; ++r) {
          int grow = row0 + wr + i * 16 + (lane >> 4) * 4 + r;
          float sc = rowscale[grow];
          #pragma unroll
          for (int j = 0; j < NJ; ++j) {
            int gcol = col0 + wc + j * 16 + fr;
            outf[(size_t)grow * (size_t)N + gcol] = acc[i][j][r] * sc + bv[j];
          }
        }
      }
    }
  }
}

extern "C" void kernel_launch(void* const* d_in, const int* in_sizes, int n_in,
                              void* d_out, int out_size, void* d_ws, size_t ws_size,
                              hipStream_t stream) {
  const float* hidden = (const float*)d_in[0];   // [16384, 512]
  const float* mkeys  = (const float*)d_in[1];   // [4096, 512]
  const float* mvals  = (const float*)d_in[2];   // [4096, 512]
  const float* Wk     = (const float*)d_in[3];   // [512, 512]
  const float* bk     = (const float*)d_in[4];   // [512]
  const float* Wo     = (const float*)d_in[5];   // [512, 512]
  const float* bo     = (const float*)d_in[6];   // [512]
  const int*   usage  = (const int*)d_in[7];     // [4096]
  (void)in_sizes; (void)n_in; (void)out_size; (void)ws_size;

  char* ws = (char*)d_ws;
  // hb region [0,16MB): bf16 hidden during q-proj; dead afterwards -> idx/meta overlay.
  u16*   hb    = (u16*)(ws + 0);            //  16,777,216  hidden bf16 (early)
  int*   idx   = (int*)(ws + 0);            //      16,384  compacted->orig map (late)
  int*   meta  = (int*)(ws + 16384);        //          16  {count, K_eff256, K/32, K/256}
  u16*   wkb   = (u16*)(ws + 16777216);     //     524,288  Wk bf16
  u16*   wob   = (u16*)(ws + 17301504);     //     524,288  Wo bf16
  u16*   mkn   = (u16*)(ws + 17825792);     //   4,194,304  compacted normalized keys bf16
  u16*   mv_c  = (u16*)(ws + 22020096);     //   4,194,304  compacted mvals bf16
  u16*   qb    = (u16*)(ws + 26214400);     //  16,777,216  q bf16 (unnormalized, +bk)
  u16*   MWt   = (u16*)(ws + 42991616);     //   4,194,304  (mvals@Wo^T)^T bf16 [512,4096]
  u16*   P     = (u16*)(ws + 47185920);     // 134,217,728  exp-scores bf16 [16384,4096]
  float* qss   = (float*)(ws + 181403648);  //     262,144  q sumsq partials [16384,4]
  float* rsqQ  = (float*)(ws + 181665792);  //      65,536  rsqrt(|q|^2+eps) [16384]
  float* lpart = (float*)(ws + 181731328);  //   2,097,152  row-sum partials [16384,32]
  float* linv  = (float*)(ws + 183828480);  //      65,536  1/rowsum [16384]
  // total: 183,894,016 bytes

  // casts
  k_f2bf<<<8192, 256, 0, stream>>>(hidden, hb, 2097152);
  k_f2bf<<<256, 256, 0, stream>>>(Wk, wkb, 65536);
  k_f2bf<<<256, 256, 0, stream>>>(Wo, wob, 65536);

  // q = hidden @ Wk^T + bk -> bf16 qb + sumsq partials (norm folded out)
  k_gemm_bt<EPI_QPROJ, 1, 64><<<dim3(4, 128), 256, 0, stream>>>(hb, wkb, 512, 512,
      nullptr, nullptr, qb, bk, qss, nullptr);
  k_rsq<<<64, 256, 0, stream>>>(qss, rsqQ);

  // compaction of the memory bank (hb now dead)
  k_compact<<<1, 256, 0, stream>>>(usage, idx, meta);
  k_gather_norm<<<1024, 256, 0, stream>>>(mkeys, idx, meta, mkn);
  k_gather<<<1024, 256, 0, stream>>>(mvals, idx, meta, mv_c);

  // MWt[h, m] = sum_v Wo[h,v] * mvals_c[m,v]  (Wo folded into V)
  k_gemm_bt<EPI_MW, 1, 64><<<dim3(16, 4), 256, 0, stream>>>(wob, mv_c, M_DIM, 512,
      meta, nullptr, MWt, nullptr, nullptr, nullptr);

  // P = exp(10 * (qb @ mkn^T) * rsqQ[r]) over active slots; partial row sums.
  // 128x256 tiles, BK=64: 8 k-iters, 8 barrier-pairs per block (was 32).
  k_gemm_bt<EPI_P, 2, 64><<<dim3(8, 128), 256, 0, stream>>>(qb, mkn, M_DIM, 512,
      meta, nullptr, P, nullptr, lpart, rsqQ);
  k_reduce_l<<<64, 256, 0, stream>>>(lpart, linv, meta);

  // out = (P @ MWt^T) * linv[r] + bo   (fp32, direct to d_out); BK=64
  k_gemm_bt<EPI_OUT, 1, 64><<<dim3(4, 128), 256, 0, stream>>>(P, MWt, 512, M_DIM,
      meta, (float*)d_out, nullptr, bo, nullptr, linv);
}

// Round 6
// 316.550 us; speedup vs baseline: 1.0347x; 1.0347x over previous
//
#include <hip/hip_runtime.h>
#include <cstdint>
#include <cstddef>

// Problem constants: B=8, S=2048, H=512, M=4096 -> R = B*S = 16384 rows.
#define H_DIM   512
#define M_DIM   4096

typedef unsigned short u16;
typedef short bf16x8 __attribute__((ext_vector_type(8)));   // 8 bf16 in 4 VGPRs
typedef float f32x4  __attribute__((ext_vector_type(4)));

typedef const __attribute__((address_space(1))) void* gp_t;
typedef __attribute__((address_space(3))) void* lp_t;

// fp32 -> bf16 round-to-nearest-even
__device__ __forceinline__ u16 f2b(float f) {
  union { float f; uint32_t u; } v; v.f = f;
  uint32_t u = v.u + (0x7FFFu + ((v.u >> 16) & 1u));
  return (u16)(u >> 16);
}

// ---------------- elementwise fp32 -> bf16 (n4 = n/4 float4 groups) ----------
__global__ void k_f2bf(const float* __restrict__ in, u16* __restrict__ out, int n4) {
  int i = blockIdx.x * blockDim.x + threadIdx.x;
  if (i < n4) {
    float4 v = ((const float4*)in)[i];
    ushort4 o;
    o.x = f2b(v.x); o.y = f2b(v.y); o.z = f2b(v.z); o.w = f2b(v.w);
    ((ushort4*)out)[i] = o;
  }
}

// ---- compaction: scan usage[4096] -> idx map + meta -------------------------
// meta[0]=count, meta[1]=K_eff=round128(count), meta[2]=K_eff/32, meta[3]=K_eff/128
__global__ void k_compact(const int* __restrict__ usage, int* __restrict__ idx,
                          int* __restrict__ meta) {
  __shared__ int cnt[256];
  int t = threadIdx.x;
  int base = t * 16;
  int c = 0;
  #pragma unroll
  for (int i = 0; i < 16; ++i) c += (usage[base + i] > 0) ? 1 : 0;
  cnt[t] = c;
  __syncthreads();
  for (int d = 1; d < 256; d <<= 1) {           // inclusive Hillis-Steele scan
    int v = (t >= d) ? cnt[t - d] : 0;
    __syncthreads();
    cnt[t] += v;
    __syncthreads();
  }
  int pos = cnt[t] - c;                          // exclusive prefix
  for (int i = 0; i < 16; ++i)
    if (usage[base + i] > 0) idx[pos++] = base + i;
  if (t == 0) {
    int total = cnt[255];
    int keff = ((total + 127) >> 7) << 7;        // 128-granular padding
    meta[0] = total; meta[1] = keff; meta[2] = keff >> 5; meta[3] = keff >> 7;
  }
}

// ---- gather + L2-normalize keys into compacted bank (zeros padding) ---------
__global__ void k_gather_norm(const float* __restrict__ in, const int* __restrict__ idx,
                              const int* __restrict__ meta, u16* __restrict__ out) {
  int j    = blockIdx.x * 4 + (threadIdx.x >> 6);
  int lane = threadIdx.x & 63;
  int count = meta[0];
  ushort4* op = (ushort4*)(out + (size_t)j * H_DIM);
  if (j >= count) {                 // wave-uniform
    ushort4 z = {0, 0, 0, 0};
    op[lane] = z; op[lane + 64] = z;
    return;
  }
  int src = idx[j];
  const float4* rp = (const float4*)(in + (size_t)src * H_DIM);
  float4 a = rp[lane];
  float4 b = rp[lane + 64];
  float ss = a.x*a.x + a.y*a.y + a.z*a.z + a.w*a.w
           + b.x*b.x + b.y*b.y + b.z*b.z + b.w*b.w;
  #pragma unroll
  for (int d = 1; d < 64; d <<= 1) ss += __shfl_xor(ss, d, 64);
  float s = rsqrtf(ss + 1e-6f);
  ushort4 oa, ob;
  oa.x = f2b(a.x*s); oa.y = f2b(a.y*s); oa.z = f2b(a.z*s); oa.w = f2b(a.w*s);
  ob.x = f2b(b.x*s); ob.y = f2b(b.y*s); ob.z = f2b(b.z*s); ob.w = f2b(b.w*s);
  op[lane]      = oa;
  op[lane + 64] = ob;
}

// ---- gather + convert: mvals fp32 rows -> compacted bf16 rows (zero pad) ----
__global__ void k_gather(const float* __restrict__ in, const int* __restrict__ idx,
                         const int* __restrict__ meta, u16* __restrict__ out) {
  int j    = blockIdx.x * 4 + (threadIdx.x >> 6);
  int lane = threadIdx.x & 63;
  int count = meta[0];
  ushort4* op = (ushort4*)(out + (size_t)j * H_DIM);
  if (j >= count) {                 // wave-uniform
    ushort4 z = {0, 0, 0, 0};
    op[lane] = z; op[lane + 64] = z;
    return;
  }
  int src = idx[j];
  const float4* rp = (const float4*)(in + (size_t)src * H_DIM);
  float4 a = rp[lane];
  float4 b = rp[lane + 64];
  ushort4 oa, ob;
  oa.x = f2b(a.x); oa.y = f2b(a.y); oa.z = f2b(a.z); oa.w = f2b(a.w);
  ob.x = f2b(b.x); ob.y = f2b(b.y); ob.z = f2b(b.z); ob.w = f2b(b.w);
  op[lane]      = oa;
  op[lane + 64] = ob;
}

// ---- rsqQ[r] = rsqrt(sum of 4 qss partials + eps) ---------------------------
__global__ void k_rsq(const float* __restrict__ qss, float* __restrict__ rsq) {
  int r = blockIdx.x * blockDim.x + threadIdx.x;
  float s = qss[r*4] + qss[r*4+1] + qss[r*4+2] + qss[r*4+3];
  rsq[r] = rsqrtf(s + 1e-6f);
}

// ---- reduce partial row sums -> reciprocal (npart = meta[3] 128-chunks) -----
__global__ void k_reduce_l(const float* __restrict__ lpart, float* __restrict__ linv,
                           const int* __restrict__ meta) {
  int r = blockIdx.x * blockDim.x + threadIdx.x;
  int n = meta[3];
  float s = 0.0f;
  for (int i = 0; i < n; ++i) s += lpart[(size_t)r * 32 + i];
  linv[r] = 1.0f / s;
}

// =============================================================================
// BT-layout GEMM: C[r,n] = sum_k A[r,k] * B[n,k]
// 128x128 tile, BK=32, 256 threads = 4 waves; wave w: rows (w>>1)*64, cols
// (w&1)*64; 16x16x32 MFMA, acc[4][4].  Conflict-free LDS: 16-row slab stored
// [chunk(4)][row(16)][8]; staged via global_load_lds, lane->(row=lane&15,
// chunk=lane>>4).
//
// SINGLE-BARRIER DOUBLE-BUFFERED K-LOOP: stage(it+1) is issued after the
// barrier and before compute(it), so the vmcnt(0) inside the NEXT iteration's
// __syncthreads waits on loads issued one full compute-phase earlier (latency
// hidden), and there is ONE barrier per k-iter instead of two.
//   Hazards: stage(it+1) overwrites buf[1-cur], last read in compute(it-1)
//   which precedes barrier(it) on every wave -> safe. compute(it) reads
//   buf[cur], drained by barrier(it)'s vmcnt(0) -> safe.
//
// EPI_QPROJ: out qb bf16 = C + bias; per-row partial sumsq -> aux[row*4+cb]
// EPI_MW   : out MWt bf16 = C  (cb-loop over meta[1]/128, step 16)
// EPI_P    : XCD-swizzled rb; P = (n<count) ? exp(10*C*rowscale[r]) : 0 -> bf16;
//            per-row partial sums -> aux[row*32+cb]  (cb-loop, step 16)
// EPI_OUT  : XCD-swizzled rb; kel=meta[1]; outf = C*rowscale[r] + bias[n] (fp32)
// =============================================================================
#define EPI_QPROJ 0
#define EPI_MW    1
#define EPI_P     2
#define EPI_OUT   3

template<int EPI>
__global__ __launch_bounds__(256)
void k_gemm_bt(const u16* __restrict__ A, const u16* __restrict__ B,
               int N, int K,
               const int* __restrict__ meta,
               float* __restrict__ outf, u16* __restrict__ outh,
               const float* __restrict__ bias,
               float* __restrict__ aux,
               const float* __restrict__ rowscale) {
  __shared__ u16 Ah[2][128 * 32];
  __shared__ u16 Bh[2][128 * 32];
  __shared__ float lsh[128];

  const int tid  = threadIdx.x;
  const int wave = tid >> 6, lane = tid & 63;
  const int wr = (wave >> 1) * 64;
  const int wc = (wave & 1) * 64;

  int rb, cb0, cb_end, cb_step, kel;
  if (EPI == EPI_QPROJ) {
    rb = blockIdx.y; cb0 = blockIdx.x; cb_end = cb0 + 1; cb_step = 1; kel = K;
  } else if (EPI == EPI_MW) {
    rb = blockIdx.y; cb0 = blockIdx.x; cb_end = meta[1] >> 7; cb_step = 16; kel = K;
  } else if (EPI == EPI_P) {
    // grid (16,128): all 16 col-blocks of a row-block on one XCD
    int id = blockIdx.x + (blockIdx.y << 4);
    int xcd = id & 7, s = id >> 3;
    rb = xcd * 16 + (s >> 4); cb0 = s & 15;
    cb_end = meta[1] >> 7; cb_step = 16; kel = K;
  } else { // EPI_OUT
    // grid (4,128): the 4 col-blocks of a row-block on one XCD
    int id = blockIdx.x + (blockIdx.y << 2);
    int xcd = id & 7, s = id >> 3;
    rb = xcd * 16 + (s >> 2); cb0 = s & 3;
    cb_end = cb0 + 1; cb_step = 1; kel = meta[1];
  }
  const int row0 = rb << 7;
  const int kiters = kel >> 5;

  // staging lane map: row = lane&15 within a 16-row slab, 32-col chunk = lane>>4
  const int srow   = lane & 15;
  const int schunk = lane >> 4;
  size_t aBase[2];
  #pragma unroll
  for (int s2 = 0; s2 < 2; ++s2)
    aBase[s2] = (size_t)(row0 + (wave + s2 * 4) * 16 + srow) * (size_t)K + schunk * 8;
  size_t bBase[2];

  const int fr = lane & 15;                       // fragment row/col within 16
  const int fbase = (lane >> 4) * 128 + fr * 8;   // LDS fragment offset

  for (int cb = cb0; cb < cb_end; cb += cb_step) {
    const int col0 = cb << 7;
    __syncthreads();                              // guard lsh/LDS reuse across cb
    if ((EPI == EPI_QPROJ || EPI == EPI_P) && tid < 128) lsh[tid] = 0.0f;

    #pragma unroll
    for (int s2 = 0; s2 < 2; ++s2)
      bBase[s2] = (size_t)(col0 + (wave + s2 * 4) * 16 + srow) * (size_t)K + schunk * 8;

    f32x4 acc[4][4];
    const f32x4 z = {0.0f, 0.0f, 0.0f, 0.0f};
    #pragma unroll
    for (int i = 0; i < 4; ++i)
      #pragma unroll
      for (int j = 0; j < 4; ++j) acc[i][j] = z;

    // stage k-chunk `k0` into buffer `buf`
    auto stage = [&](int buf, int k0) {
      #pragma unroll
      for (int s2 = 0; s2 < 2; ++s2)
        __builtin_amdgcn_global_load_lds((gp_t)(A + aBase[s2] + k0),
            (lp_t)&Ah[buf][(wave + s2 * 4) * 512], 16, 0, 0);
      #pragma unroll
      for (int s2 = 0; s2 < 2; ++s2)
        __builtin_amdgcn_global_load_lds((gp_t)(B + bBase[s2] + k0),
            (lp_t)&Bh[buf][(wave + s2 * 4) * 512], 16, 0, 0);
    };

    stage(0, 0);                                  // prologue
    for (int it = 0; it < kiters; ++it) {
      const int cur = it & 1;
      __syncthreads();           // drains stage(it); aligns waves (ONE barrier/iter)
      if (it + 1 < kiters) stage(1 - cur, (it + 1) << 5);

      bf16x8 af[4], bfv[4];
      #pragma unroll
      for (int i = 0; i < 4; ++i)
        af[i] = *(const bf16x8*)&Ah[cur][((wr >> 4) + i) * 512 + fbase];
      #pragma unroll
      for (int j = 0; j < 4; ++j)
        bfv[j] = *(const bf16x8*)&Bh[cur][((wc >> 4) + j) * 512 + fbase];
      #pragma unroll
      for (int i = 0; i < 4; ++i)
        #pragma unroll
        for (int j = 0; j < 4; ++j)
          acc[i][j] = __builtin_amdgcn_mfma_f32_16x16x32_bf16(af[i], bfv[j], acc[i][j], 0, 0, 0);
    }

    // Epilogue. C/D layout per 16x16 tile: col = lane&15, row = (lane>>4)*4 + reg.
    if (EPI == EPI_QPROJ) {
      float bv[4];
      #pragma unroll
      for (int j = 0; j < 4; ++j) bv[j] = bias[col0 + wc + j * 16 + fr];
      #pragma unroll
      for (int i = 0; i < 4; ++i) {
        #pragma unroll
        for (int r = 0; r < 4; ++r) {
          int lrow = wr + i * 16 + (lane >> 4) * 4 + r;
          size_t grow = (size_t)(row0 + lrow);
          float s = 0.0f;
          #pragma unroll
          for (int j = 0; j < 4; ++j) {
            int gcol = col0 + wc + j * 16 + fr;
            float v = acc[i][j][r] + bv[j];
            outh[grow * (size_t)N + gcol] = f2b(v);
            s += v * v;
          }
          #pragma unroll
          for (int d = 1; d < 16; d <<= 1) s += __shfl_xor(s, d, 64);
          if (fr == 0) atomicAdd(&lsh[lrow], s);
        }
      }
      __syncthreads();
      if (tid < 128) aux[(size_t)(row0 + tid) * 4 + cb] = lsh[tid];
    } else if (EPI == EPI_MW) {
      #pragma unroll
      for (int i = 0; i < 4; ++i) {
        #pragma unroll
        for (int r = 0; r < 4; ++r) {
          int grow = row0 + wr + i * 16 + (lane >> 4) * 4 + r;
          #pragma unroll
          for (int j = 0; j < 4; ++j) {
            int gcol = col0 + wc + j * 16 + fr;
            outh[(size_t)grow * (size_t)N + gcol] = f2b(acc[i][j][r]);
          }
        }
      }
    } else if (EPI == EPI_P) {
      const int count = meta[0];
      #pragma unroll
      for (int i = 0; i < 4; ++i) {
        #pragma unroll
        for (int r = 0; r < 4; ++r) {
          int lrow = wr + i * 16 + (lane >> 4) * 4 + r;
          size_t grow = (size_t)(row0 + lrow);
          float rq10 = rowscale[grow] * 10.0f;
          float s = 0.0f;
          #pragma unroll
          for (int j = 0; j < 4; ++j) {
            int gcol = col0 + wc + j * 16 + fr;
            float p = (gcol < count) ? __expf(acc[i][j][r] * rq10) : 0.0f;
            outh[grow * (size_t)N + gcol] = f2b(p);
            s += p;
          }
          #pragma unroll
          for (int d = 1; d < 16; d <<= 1) s += __shfl_xor(s, d, 64);
          if (fr == 0) atomicAdd(&lsh[lrow], s);
        }
      }
      __syncthreads();
      if (tid < 128) aux[(size_t)(row0 + tid) * 32 + cb] = lsh[tid];
    } else {  // EPI_OUT
      float bv[4];
      #pragma unroll
      for (int j = 0; j < 4; ++j) bv[j] = bias[col0 + wc + j * 16 + fr];
      #pragma unroll
      for (int i = 0; i < 4; ++i) {
        #pragma unroll
        for (int r = 0; r < 4; ++r) {
          int grow = row0 + wr + i * 16 + (lane >> 4) * 4 + r;
          float sc = rowscale[grow];
          #pragma unroll
          for (int j = 0; j < 4; ++j) {
            int gcol = col0 + wc + j * 16 + fr;
            outf[(size_t)grow * (size_t)N + gcol] = acc[i][j][r] * sc + bv[j];
          }
        }
      }
    }
  }
}

extern "C" void kernel_launch(void* const* d_in, const int* in_sizes, int n_in,
                              void* d_out, int out_size, void* d_ws, size_t ws_size,
                              hipStream_t stream) {
  const float* hidden = (const float*)d_in[0];   // [16384, 512]
  const float* mkeys  = (const float*)d_in[1];   // [4096, 512]
  const float* mvals  = (const float*)d_in[2];   // [4096, 512]
  const float* Wk     = (const float*)d_in[3];   // [512, 512]
  const float* bk     = (const float*)d_in[4];   // [512]
  const float* Wo     = (const float*)d_in[5];   // [512, 512]
  const float* bo     = (const float*)d_in[6];   // [512]
  const int*   usage  = (const int*)d_in[7];     // [4096]
  (void)in_sizes; (void)n_in; (void)out_size; (void)ws_size;

  char* ws = (char*)d_ws;
  // hb region [0,16MB): bf16 hidden during q-proj; dead afterwards -> idx/meta overlay.
  u16*   hb    = (u16*)(ws + 0);            //  16,777,216  hidden bf16 (early)
  int*   idx   = (int*)(ws + 0);            //      16,384  compacted->orig map (late)
  int*   meta  = (int*)(ws + 16384);        //          16  {count, K_eff, K/32, K/128}
  u16*   wkb   = (u16*)(ws + 16777216);     //     524,288  Wk bf16
  u16*   wob   = (u16*)(ws + 17301504);     //     524,288  Wo bf16
  u16*   mkn   = (u16*)(ws + 17825792);     //   4,194,304  compacted normalized keys bf16
  u16*   mv_c  = (u16*)(ws + 22020096);     //   4,194,304  compacted mvals bf16
  u16*   qb    = (u16*)(ws + 26214400);     //  16,777,216  q bf16 (unnormalized, +bk)
  u16*   MWt   = (u16*)(ws + 42991616);     //   4,194,304  (mvals@Wo^T)^T bf16 [512,4096]
  u16*   P     = (u16*)(ws + 47185920);     // 134,217,728  exp-scores bf16 [16384,4096]
  float* qss   = (float*)(ws + 181403648);  //     262,144  q sumsq partials [16384,4]
  float* rsqQ  = (float*)(ws + 181665792);  //      65,536  rsqrt(|q|^2+eps) [16384]
  float* lpart = (float*)(ws + 181731328);  //   2,097,152  row-sum partials [16384,32]
  float* linv  = (float*)(ws + 183828480);  //      65,536  1/rowsum [16384]
  // total: 183,894,016 bytes

  // casts
  k_f2bf<<<8192, 256, 0, stream>>>(hidden, hb, 2097152);
  k_f2bf<<<256, 256, 0, stream>>>(Wk, wkb, 65536);
  k_f2bf<<<256, 256, 0, stream>>>(Wo, wob, 65536);

  // q = hidden @ Wk^T + bk -> bf16 qb + sumsq partials (norm folded out)
  k_gemm_bt<EPI_QPROJ><<<dim3(4, 128), 256, 0, stream>>>(hb, wkb, 512, 512,
      nullptr, nullptr, qb, bk, qss, nullptr);
  k_rsq<<<64, 256, 0, stream>>>(qss, rsqQ);

  // compaction of the memory bank (hb now dead)
  k_compact<<<1, 256, 0, stream>>>(usage, idx, meta);
  k_gather_norm<<<1024, 256, 0, stream>>>(mkeys, idx, meta, mkn);
  k_gather<<<1024, 256, 0, stream>>>(mvals, idx, meta, mv_c);

  // MWt[h, m] = sum_v Wo[h,v] * mvals_c[m,v]  (Wo folded into V)
  k_gemm_bt<EPI_MW><<<dim3(16, 4), 256, 0, stream>>>(wob, mv_c, M_DIM, 512,
      meta, nullptr, MWt, nullptr, nullptr, nullptr);

  // P = exp(10 * (qb @ mkn^T) * rsqQ[r]) over active slots; partial row sums
  k_gemm_bt<EPI_P><<<dim3(16, 128), 256, 0, stream>>>(qb, mkn, M_DIM, 512,
      meta, nullptr, P, nullptr, lpart, rsqQ);
  k_reduce_l<<<64, 256, 0, stream>>>(lpart, linv, meta);

  // out = (P @ MWt^T) * linv[r] + bo   (fp32, direct to d_out)
  k_gemm_bt<EPI_OUT><<<dim3(4, 128), 256, 0, stream>>>(P, MWt, 512, M_DIM,
      meta, (float*)d_out, nullptr, bo, nullptr, linv);
}

// Round 7
// 293.608 us; speedup vs baseline: 1.1156x; 1.0781x over previous
//
#include <hip/hip_runtime.h>
#include <cstdint>
#include <cstddef>

// Problem constants: B=8, S=2048, H=512, M=4096 -> R = B*S = 16384 rows.
#define H_DIM   512
#define M_DIM   4096

typedef unsigned short u16;
typedef short bf16x8 __attribute__((ext_vector_type(8)));   // 8 bf16 in 4 VGPRs
typedef float f32x4  __attribute__((ext_vector_type(4)));

// fp32 -> bf16 round-to-nearest-even
__device__ __forceinline__ u16 f2b(float f) {
  union { float f; uint32_t u; } v; v.f = f;
  uint32_t u = v.u + (0x7FFFu + ((v.u >> 16) & 1u));
  return (u16)(u >> 16);
}

// ---------------- elementwise fp32 -> bf16 (n4 = n/4 float4 groups) ----------
__global__ void k_f2bf(const float* __restrict__ in, u16* __restrict__ out, int n4) {
  int i = blockIdx.x * blockDim.x + threadIdx.x;
  if (i < n4) {
    float4 v = ((const float4*)in)[i];
    ushort4 o;
    o.x = f2b(v.x); o.y = f2b(v.y); o.z = f2b(v.z); o.w = f2b(v.w);
    ((ushort4*)out)[i] = o;
  }
}

// ---- both weight casts in one launch: 512 blocks x 256 thr, 2x 65536 f4 -----
__global__ void k_f2bf_ww(const float* __restrict__ wk, const float* __restrict__ wo,
                          u16* __restrict__ owk, u16* __restrict__ owo) {
  int i = blockIdx.x * blockDim.x + threadIdx.x;
  const float* src = (i < 65536) ? wk : wo;
  u16* dst = (i < 65536) ? owk : owo;
  int j = i & 65535;
  float4 v = ((const float4*)src)[j];
  ushort4 o;
  o.x = f2b(v.x); o.y = f2b(v.y); o.z = f2b(v.z); o.w = f2b(v.w);
  ((ushort4*)dst)[j] = o;
}

// ---- compaction: scan usage[4096] -> idx map + meta -------------------------
// meta[0]=count, meta[1]=K_eff=round128(count), meta[2]=K_eff/32, meta[3]=K_eff/128
__global__ void k_compact(const int* __restrict__ usage, int* __restrict__ idx,
                          int* __restrict__ meta) {
  __shared__ int cnt[256];
  int t = threadIdx.x;
  int base = t * 16;
  int c = 0;
  #pragma unroll
  for (int i = 0; i < 16; ++i) c += (usage[base + i] > 0) ? 1 : 0;
  cnt[t] = c;
  __syncthreads();
  for (int d = 1; d < 256; d <<= 1) {           // inclusive Hillis-Steele scan
    int v = (t >= d) ? cnt[t - d] : 0;
    __syncthreads();
    cnt[t] += v;
    __syncthreads();
  }
  int pos = cnt[t] - c;                          // exclusive prefix
  for (int i = 0; i < 16; ++i)
    if (usage[base + i] > 0) idx[pos++] = base + i;
  if (t == 0) {
    int total = cnt[255];
    int keff = ((total + 127) >> 7) << 7;        // 128-granular padding
    meta[0] = total; meta[1] = keff; meta[2] = keff >> 5; meta[3] = keff >> 7;
  }
}

// ---- gather both: keys (L2-normalized) AND vals (plain) -> compacted bf16 ---
__global__ void k_gather_both(const float* __restrict__ keys, const float* __restrict__ vals,
                              const int* __restrict__ idx, const int* __restrict__ meta,
                              u16* __restrict__ okeys, u16* __restrict__ ovals) {
  int j    = blockIdx.x * 4 + (threadIdx.x >> 6);
  int lane = threadIdx.x & 63;
  int count = meta[0];
  ushort4* kp = (ushort4*)(okeys + (size_t)j * H_DIM);
  ushort4* vp = (ushort4*)(ovals + (size_t)j * H_DIM);
  if (j >= count) {                 // wave-uniform
    ushort4 z = {0, 0, 0, 0};
    kp[lane] = z; kp[lane + 64] = z;
    vp[lane] = z; vp[lane + 64] = z;
    return;
  }
  int src = idx[j];
  // keys: normalize
  const float4* rp = (const float4*)(keys + (size_t)src * H_DIM);
  float4 a = rp[lane];
  float4 b = rp[lane + 64];
  float ss = a.x*a.x + a.y*a.y + a.z*a.z + a.w*a.w
           + b.x*b.x + b.y*b.y + b.z*b.z + b.w*b.w;
  #pragma unroll
  for (int d = 1; d < 64; d <<= 1) ss += __shfl_xor(ss, d, 64);
  float s = rsqrtf(ss + 1e-6f);
  ushort4 oa, ob;
  oa.x = f2b(a.x*s); oa.y = f2b(a.y*s); oa.z = f2b(a.z*s); oa.w = f2b(a.w*s);
  ob.x = f2b(b.x*s); ob.y = f2b(b.y*s); ob.z = f2b(b.z*s); ob.w = f2b(b.w*s);
  kp[lane]      = oa;
  kp[lane + 64] = ob;
  // vals: plain cast
  const float4* vr = (const float4*)(vals + (size_t)src * H_DIM);
  float4 c0 = vr[lane];
  float4 c1 = vr[lane + 64];
  ushort4 va, vb;
  va.x = f2b(c0.x); va.y = f2b(c0.y); va.z = f2b(c0.z); va.w = f2b(c0.w);
  vb.x = f2b(c1.x); vb.y = f2b(c1.y); vb.z = f2b(c1.z); vb.w = f2b(c1.w);
  vp[lane]      = va;
  vp[lane + 64] = vb;
}

// ---- rsqQ[r] = rsqrt(sum of 4 qss partials + eps) ---------------------------
__global__ void k_rsq(const float* __restrict__ qss, float* __restrict__ rsq) {
  int r = blockIdx.x * blockDim.x + threadIdx.x;
  float s = qss[r*4] + qss[r*4+1] + qss[r*4+2] + qss[r*4+3];
  rsq[r] = rsqrtf(s + 1e-6f);
}

// ---- reduce partial row sums -> reciprocal (npart = meta[3] 128-chunks) -----
__global__ void k_reduce_l(const float* __restrict__ lpart, float* __restrict__ linv,
                           const int* __restrict__ meta) {
  int r = blockIdx.x * blockDim.x + threadIdx.x;
  int n = meta[3];
  float s = 0.0f;
  for (int i = 0; i < n; ++i) s += lpart[(size_t)r * 32 + i];
  linv[r] = 1.0f / s;
}

// =============================================================================
// BT-layout GEMM: C[r,n] = sum_k A[r,k] * B[n,k]
// 128x128 tile, BK=32, 256 threads = 4 waves; wave w: rows (w>>1)*64, cols
// (w&1)*64; 16x16x32 MFMA, acc[4][4].  Conflict-free LDS: 16-row slab stored
// [chunk(4)][row(16)][8]; lane -> (row=lane&15, chunk=lane>>4).
//
// REGISTER-STAGED SINGLE-BARRIER DOUBLE BUFFER: global loads land in VGPRs
// (wave-private!), so the per-iter __syncthreads needs only lgkmcnt(0) —
// NO vmcnt(0) drain (that drain was the structural stall with
// global_load_lds, where the DMA target is LDS). The vmcnt wait moves to the
// ds_write consuming the registers, whose loads were issued one full
// compute-phase earlier -> latency hidden behind MFMA.
//   Hazards (1 barrier/iter, 2 buffers): write(it+2 -> buf) occurs after
//   barrier(it+1); every wave's reads(it -> buf) precede its barrier(it+1),
//   and each wave's own lgkmcnt(0) at the barrier retires its reads -> safe.
//   write(it+1 -> buf^1) overlaps reads(it -> buf): disjoint buffers -> safe.
//
// EPI_QPROJ: out qb bf16 = C + bias; per-row partial sumsq -> aux[row*4+cb]
// EPI_MW   : out MWt bf16 = C  (cb-loop over meta[1]/128, step 16)
// EPI_P    : XCD-swizzled rb; P = (n<count) ? exp(10*C*rowscale[r]) : 0 -> bf16;
//            per-row partial sums -> aux[row*32+cb]  (cb-loop, step 16)
// EPI_OUT  : XCD-swizzled rb; kel=meta[1]; outf = C*rowscale[r] + bias[n] (fp32)
// =============================================================================
#define EPI_QPROJ 0
#define EPI_MW    1
#define EPI_P     2
#define EPI_OUT   3

template<int EPI>
__global__ __launch_bounds__(256)
void k_gemm_bt(const u16* __restrict__ A, const u16* __restrict__ B,
               int N, int K,
               const int* __restrict__ meta,
               float* __restrict__ outf, u16* __restrict__ outh,
               const float* __restrict__ bias,
               float* __restrict__ aux,
               const float* __restrict__ rowscale) {
  __shared__ u16 Ah[2][128 * 32];
  __shared__ u16 Bh[2][128 * 32];
  __shared__ float lsh[128];

  const int tid  = threadIdx.x;
  const int wave = tid >> 6, lane = tid & 63;
  const int wr = (wave >> 1) * 64;
  const int wc = (wave & 1) * 64;

  int rb, cb0, cb_end, cb_step, kel;
  if (EPI == EPI_QPROJ) {
    rb = blockIdx.y; cb0 = blockIdx.x; cb_end = cb0 + 1; cb_step = 1; kel = K;
  } else if (EPI == EPI_MW) {
    rb = blockIdx.y; cb0 = blockIdx.x; cb_end = meta[1] >> 7; cb_step = 16; kel = K;
  } else if (EPI == EPI_P) {
    // grid (16,128): all 16 col-blocks of a row-block on one XCD
    int id = blockIdx.x + (blockIdx.y << 4);
    int xcd = id & 7, s = id >> 3;
    rb = xcd * 16 + (s >> 4); cb0 = s & 15;
    cb_end = meta[1] >> 7; cb_step = 16; kel = K;
  } else { // EPI_OUT
    // grid (4,128): the 4 col-blocks of a row-block on one XCD
    int id = blockIdx.x + (blockIdx.y << 2);
    int xcd = id & 7, s = id >> 3;
    rb = xcd * 16 + (s >> 2); cb0 = s & 3;
    cb_end = cb0 + 1; cb_step = 1; kel = meta[1];
  }
  const int row0 = rb << 7;
  const int kiters = kel >> 5;

  // staging lane map: row = lane&15 within a 16-row slab, 32-col chunk = lane>>4
  const int srow   = lane & 15;
  const int schunk = lane >> 4;
  const int lds_off = schunk * 128 + srow * 8;    // within a 512-u16 slab
  size_t aBase[2];
  #pragma unroll
  for (int s2 = 0; s2 < 2; ++s2)
    aBase[s2] = (size_t)(row0 + (wave + s2 * 4) * 16 + srow) * (size_t)K + schunk * 8;
  size_t bBase[2];

  const int fr = lane & 15;                       // fragment row/col within 16
  const int fbase = (lane >> 4) * 128 + fr * 8;   // LDS fragment offset

  for (int cb = cb0; cb < cb_end; cb += cb_step) {
    const int col0 = cb << 7;
    __syncthreads();                              // guard lsh/LDS reuse across cb
    if ((EPI == EPI_QPROJ || EPI == EPI_P) && tid < 128) lsh[tid] = 0.0f;

    #pragma unroll
    for (int s2 = 0; s2 < 2; ++s2)
      bBase[s2] = (size_t)(col0 + (wave + s2 * 4) * 16 + srow) * (size_t)K + schunk * 8;

    f32x4 acc[4][4];
    const f32x4 z = {0.0f, 0.0f, 0.0f, 0.0f};
    #pragma unroll
    for (int i = 0; i < 4; ++i)
      #pragma unroll
      for (int j = 0; j < 4; ++j) acc[i][j] = z;

    bf16x8 rA[2], rB[2];
    auto gload = [&](int k0) {
      #pragma unroll
      for (int s2 = 0; s2 < 2; ++s2) rA[s2] = *(const bf16x8*)(A + aBase[s2] + k0);
      #pragma unroll
      for (int s2 = 0; s2 < 2; ++s2) rB[s2] = *(const bf16x8*)(B + bBase[s2] + k0);
    };

    gload(0);                                     // prologue (vmcnt exposed once)
    for (int it = 0; it < kiters; ++it) {
      const int cur = it & 1;
      // commit staged regs to LDS (vmcnt wait here targets loads issued one
      // compute-phase ago -> hidden)
      #pragma unroll
      for (int s2 = 0; s2 < 2; ++s2)
        *(bf16x8*)&Ah[cur][(wave + s2 * 4) * 512 + lds_off] = rA[s2];
      #pragma unroll
      for (int s2 = 0; s2 < 2; ++s2)
        *(bf16x8*)&Bh[cur][(wave + s2 * 4) * 512 + lds_off] = rB[s2];
      if (it + 1 < kiters) gload((it + 1) << 5);  // next loads in flight
      __syncthreads();                            // lgkmcnt only — no vmcnt drain

      bf16x8 af[4], bfv[4];
      #pragma unroll
      for (int i = 0; i < 4; ++i)
        af[i] = *(const bf16x8*)&Ah[cur][((wr >> 4) + i) * 512 + fbase];
      #pragma unroll
      for (int j = 0; j < 4; ++j)
        bfv[j] = *(const bf16x8*)&Bh[cur][((wc >> 4) + j) * 512 + fbase];
      #pragma unroll
      for (int i = 0; i < 4; ++i)
        #pragma unroll
        for (int j = 0; j < 4; ++j)
          acc[i][j] = __builtin_amdgcn_mfma_f32_16x16x32_bf16(af[i], bfv[j], acc[i][j], 0, 0, 0);
    }

    // Epilogue. C/D layout per 16x16 tile: col = lane&15, row = (lane>>4)*4 + reg.
    if (EPI == EPI_QPROJ) {
      float bv[4];
      #pragma unroll
      for (int j = 0; j < 4; ++j) bv[j] = bias[col0 + wc + j * 16 + fr];
      #pragma unroll
      for (int i = 0; i < 4; ++i) {
        #pragma unroll
        for (int r = 0; r < 4; ++r) {
          int lrow = wr + i * 16 + (lane >> 4) * 4 + r;
          size_t grow = (size_t)(row0 + lrow);
          float s = 0.0f;
          #pragma unroll
          for (int j = 0; j < 4; ++j) {
            int gcol = col0 + wc + j * 16 + fr;
            float v = acc[i][j][r] + bv[j];
            outh[grow * (size_t)N + gcol] = f2b(v);
            s += v * v;
          }
          #pragma unroll
          for (int d = 1; d < 16; d <<= 1) s += __shfl_xor(s, d, 64);
          if (fr == 0) atomicAdd(&lsh[lrow], s);
        }
      }
      __syncthreads();
      if (tid < 128) aux[(size_t)(row0 + tid) * 4 + cb] = lsh[tid];
    } else if (EPI == EPI_MW) {
      #pragma unroll
      for (int i = 0; i < 4; ++i) {
        #pragma unroll
        for (int r = 0; r < 4; ++r) {
          int grow = row0 + wr + i * 16 + (lane >> 4) * 4 + r;
          #pragma unroll
          for (int j = 0; j < 4; ++j) {
            int gcol = col0 + wc + j * 16 + fr;
            outh[(size_t)grow * (size_t)N + gcol] = f2b(acc[i][j][r]);
          }
        }
      }
    } else if (EPI == EPI_P) {
      const int count = meta[0];
      #pragma unroll
      for (int i = 0; i < 4; ++i) {
        #pragma unroll
        for (int r = 0; r < 4; ++r) {
          int lrow = wr + i * 16 + (lane >> 4) * 4 + r;
          size_t grow = (size_t)(row0 + lrow);
          float rq10 = rowscale[grow] * 10.0f;
          float s = 0.0f;
          #pragma unroll
          for (int j = 0; j < 4; ++j) {
            int gcol = col0 + wc + j * 16 + fr;
            float p = (gcol < count) ? __expf(acc[i][j][r] * rq10) : 0.0f;
            outh[grow * (size_t)N + gcol] = f2b(p);
            s += p;
          }
          #pragma unroll
          for (int d = 1; d < 16; d <<= 1) s += __shfl_xor(s, d, 64);
          if (fr == 0) atomicAdd(&lsh[lrow], s);
        }
      }
      __syncthreads();
      if (tid < 128) aux[(size_t)(row0 + tid) * 32 + cb] = lsh[tid];
    } else {  // EPI_OUT
      float bv[4];
      #pragma unroll
      for (int j = 0; j < 4; ++j) bv[j] = bias[col0 + wc + j * 16 + fr];
      #pragma unroll
      for (int i = 0; i < 4; ++i) {
        #pragma unroll
        for (int r = 0; r < 4; ++r) {
          int grow = row0 + wr + i * 16 + (lane >> 4) * 4 + r;
          float sc = rowscale[grow];
          #pragma unroll
          for (int j = 0; j < 4; ++j) {
            int gcol = col0 + wc + j * 16 + fr;
            outf[(size_t)grow * (size_t)N + gcol] = acc[i][j][r] * sc + bv[j];
          }
        }
      }
    }
  }
}

extern "C" void kernel_launch(void* const* d_in, const int* in_sizes, int n_in,
                              void* d_out, int out_size, void* d_ws, size_t ws_size,
                              hipStream_t stream) {
  const float* hidden = (const float*)d_in[0];   // [16384, 512]
  const float* mkeys  = (const float*)d_in[1];   // [4096, 512]
  const float* mvals  = (const float*)d_in[2];   // [4096, 512]
  const float* Wk     = (const float*)d_in[3];   // [512, 512]
  const float* bk     = (const float*)d_in[4];   // [512]
  const float* Wo     = (const float*)d_in[5];   // [512, 512]
  const float* bo     = (const float*)d_in[6];   // [512]
  const int*   usage  = (const int*)d_in[7];     // [4096]
  (void)in_sizes; (void)n_in; (void)out_size; (void)ws_size;

  char* ws = (char*)d_ws;
  // hb region [0,16MB): bf16 hidden during q-proj; dead afterwards -> idx/meta overlay.
  u16*   hb    = (u16*)(ws + 0);            //  16,777,216  hidden bf16 (early)
  int*   idx   = (int*)(ws + 0);            //      16,384  compacted->orig map (late)
  int*   meta  = (int*)(ws + 16384);        //          16  {count, K_eff, K/32, K/128}
  u16*   wkb   = (u16*)(ws + 16777216);     //     524,288  Wk bf16
  u16*   wob   = (u16*)(ws + 17301504);     //     524,288  Wo bf16
  u16*   mkn   = (u16*)(ws + 17825792);     //   4,194,304  compacted normalized keys bf16
  u16*   mv_c  = (u16*)(ws + 22020096);     //   4,194,304  compacted mvals bf16
  u16*   qb    = (u16*)(ws + 26214400);     //  16,777,216  q bf16 (unnormalized, +bk)
  u16*   MWt   = (u16*)(ws + 42991616);     //   4,194,304  (mvals@Wo^T)^T bf16 [512,4096]
  u16*   P     = (u16*)(ws + 47185920);     // 134,217,728  exp-scores bf16 [16384,4096]
  float* qss   = (float*)(ws + 181403648);  //     262,144  q sumsq partials [16384,4]
  float* rsqQ  = (float*)(ws + 181665792);  //      65,536  rsqrt(|q|^2+eps) [16384]
  float* lpart = (float*)(ws + 181731328);  //   2,097,152  row-sum partials [16384,32]
  float* linv  = (float*)(ws + 183828480);  //      65,536  1/rowsum [16384]
  // total: 183,894,016 bytes

  // casts
  k_f2bf<<<8192, 256, 0, stream>>>(hidden, hb, 2097152);
  k_f2bf_ww<<<512, 256, 0, stream>>>(Wk, Wo, wkb, wob);

  // q = hidden @ Wk^T + bk -> bf16 qb + sumsq partials (norm folded out)
  k_gemm_bt<EPI_QPROJ><<<dim3(4, 128), 256, 0, stream>>>(hb, wkb, 512, 512,
      nullptr, nullptr, qb, bk, qss, nullptr);
  k_rsq<<<64, 256, 0, stream>>>(qss, rsqQ);

  // compaction of the memory bank (hb now dead)
  k_compact<<<1, 256, 0, stream>>>(usage, idx, meta);
  k_gather_both<<<1024, 256, 0, stream>>>(mkeys, mvals, idx, meta, mkn, mv_c);

  // MWt[h, m] = sum_v Wo[h,v] * mvals_c[m,v]  (Wo folded into V)
  k_gemm_bt<EPI_MW><<<dim3(16, 4), 256, 0, stream>>>(wob, mv_c, M_DIM, 512,
      meta, nullptr, MWt, nullptr, nullptr, nullptr);

  // P = exp(10 * (qb @ mkn^T) * rsqQ[r]) over active slots; partial row sums
  k_gemm_bt<EPI_P><<<dim3(16, 128), 256, 0, stream>>>(qb, mkn, M_DIM, 512,
      meta, nullptr, P, nullptr, lpart, rsqQ);
  k_reduce_l<<<64, 256, 0, stream>>>(lpart, linv, meta);

  // out = (P @ MWt^T) * linv[r] + bo   (fp32, direct to d_out)
  k_gemm_bt<EPI_OUT><<<dim3(4, 128), 256, 0, stream>>>(P, MWt, 512, M_DIM,
      meta, (float*)d_out, nullptr, bo, nullptr, linv);
}